// Round 11
// baseline (322.104 us; speedup 1.0000x reference)
//
#include <hip/hip_runtime.h>
#include <hip/hip_bf16.h>

static inline int ceil_div(int a, int b) { return (a + b - 1) / b; }

// ================= Atomic-free CSR build: 2-level MSD bucket sort =================
// Bucket = dst >> 8 (nbucket = ceil(n/256) <= 256). No global atomics anywhere.
// Edges packed as u32: src (16b) | (dst & 255) << 16.   (n < 65536 required)

#define SORT_BLOCKS 256

// K0: per-block LDS histogram of coarse buckets
__global__ __launch_bounds__(256) void bucket_hist_kernel(const int* __restrict__ ei,
        int* __restrict__ hist_b, int E, int nbucket, int chunk) {
    __shared__ int h[256];
    const int t = (int)threadIdx.x;
    h[t] = 0;
    __syncthreads();
    const int b = blockIdx.x;
    const int e0 = b * chunk, e1 = min(E, e0 + chunk);
    for (int e = e0 + t; e < e1; e += 256)
        atomicAdd(&h[ei[E + e] >> 8], 1);              // LDS atomic, ~1.3 thr/ctr
    __syncthreads();
    if (t < nbucket) hist_b[t * SORT_BLOCKS + b] = h[t];
}

// K1: one block per bucket. Coalesced row load -> block scan -> in-place exclusive
// per-block bases + row total to btot.
__global__ __launch_bounds__(256) void row_scan_kernel(int* __restrict__ hist_b,
        int* __restrict__ btot) {
    const int i = blockIdx.x;            // bucket
    const int t = (int)threadIdx.x;      // block column
    int c = hist_b[i * SORT_BLOCKS + t];
    int v = c;
    const int lane = t & 63, wid = t >> 6;
    #pragma unroll
    for (int off = 1; off < 64; off <<= 1) {
        int u = __shfl_up(v, off);
        if (lane >= off) v += u;
    }
    __shared__ int wsum[4];
    if (lane == 63) wsum[wid] = v;
    __syncthreads();
    int wbase = 0;
    #pragma unroll
    for (int w = 0; w < 4; ++w) if (w < wid) wbase += wsum[w];
    v += wbase;                           // inclusive prefix over row
    hist_b[i * SORT_BLOCKS + t] = v - c;  // exclusive base for (bucket i, block t)
    if (t == 255) btot[i] = v;            // row total
}

// K2: scatter packed (src, dst&255) into bucket-grouped tmp[].
// Each block redundantly scans btot in LDS (cheap, parallel) -> bstart; block 0
// publishes bstart to global for K3. Disjoint slots per block -> no global atomics.
__global__ __launch_bounds__(256) void bucket_scatter_kernel(const int* __restrict__ ei,
        const int* __restrict__ rel_base, const int* __restrict__ btot,
        int* __restrict__ bstart, unsigned int* __restrict__ tmp,
        int E, int nbucket, int chunk) {
    __shared__ int sc[256];
    __shared__ int cur[256];
    const int t = (int)threadIdx.x;
    const int b = blockIdx.x;
    int tot = (t < nbucket) ? btot[t] : 0;
    sc[t] = tot;
    __syncthreads();
    for (int off = 1; off < 256; off <<= 1) {          // inclusive Hillis-Steele
        int v = (t >= off) ? sc[t - off] : 0;
        __syncthreads();
        sc[t] += v;
        __syncthreads();
    }
    const int my_bstart = sc[t] - tot;                 // exclusive
    if (b == 0) {
        if (t < nbucket) bstart[t] = my_bstart;
        if (t == 0) bstart[nbucket] = E;
    }
    if (t < nbucket) cur[t] = my_bstart + rel_base[t * SORT_BLOCKS + b];
    __syncthreads();
    const int e0 = b * chunk, e1 = min(E, e0 + chunk);
    for (int e = e0 + t; e < e1; e += 256) {
        int s = ei[e];
        int d = ei[E + e];
        int pos = atomicAdd(&cur[d >> 8], 1);           // LDS atomic
        tmp[pos] = (unsigned int)s | ((unsigned int)(d & 255) << 16);
    }
}

// K3: one block per bucket. LDS 256-bin histogram + scan -> rowptr/dinv/colidx.
__global__ __launch_bounds__(256) void csr_build_kernel(const unsigned int* __restrict__ tmp,
        const int* __restrict__ bucket_start, int* __restrict__ rowptr,
        float* __restrict__ dinv, int* __restrict__ colidx, int n, int E) {
    __shared__ int hist[256], sc[256], cur[256];
    const int h = blockIdx.x;
    const int t = (int)threadIdx.x;
    hist[t] = 0;
    __syncthreads();
    const int e0 = bucket_start[h], e1 = bucket_start[h + 1];
    for (int e = e0 + t; e < e1; e += 256)
        atomicAdd(&hist[(tmp[e] >> 16) & 255], 1);      // LDS atomic
    __syncthreads();
    sc[t] = hist[t];
    __syncthreads();
    for (int off = 1; off < 256; off <<= 1) {           // inclusive scan
        int v = (t >= off) ? sc[t - off] : 0;
        __syncthreads();
        sc[t] += v;
        __syncthreads();
    }
    const int excl = sc[t] - hist[t];
    const int node = h * 256 + t;
    if (node < n) {
        rowptr[node] = e0 + excl;
        dinv[node] = rsqrtf((float)(hist[t] + 1));      // +1 self-loop
    }
    if (h == 0 && t == 0) rowptr[n] = E;
    cur[t] = excl;
    __syncthreads();
    for (int e = e0 + t; e < e1; e += 256) {
        unsigned int p = tmp[e];
        int pos = e0 + atomicAdd(&cur[(p >> 16) & 255], 1);   // LDS atomic
        colidx[pos] = (int)(p & 0xFFFFu);
    }
}

// ---------------- fp32 tiled GEMM: out[M,N] = A[M,K] @ W[K,N] (+bias), fp32 or bf16 out ----

template<int K, int N, bool BIAS, bool OUT_BF16>
__global__ __launch_bounds__(256) void gemm_kernel(const float* __restrict__ A,
        const float* __restrict__ W, const float* __restrict__ bias,
        void* __restrict__ out_, int M) {
    __shared__ float As[16][68];   // [k][m], padded
    __shared__ float Bs[16][68];   // [k][n]
    const int bm = blockIdx.x * 64;
    const int bn = blockIdx.y * 64;
    const int tid = (int)threadIdx.x;
    const int tx = tid & 15;
    const int ty = tid >> 4;
    float acc[4][4] = {};
    for (int k0 = 0; k0 < K; k0 += 16) {
        {   // A tile: 64 rows x 16 k, float4-coalesced, stored transposed
            int m   = tid >> 2;
            int kk4 = (tid & 3) * 4;
            float4 v = make_float4(0.f, 0.f, 0.f, 0.f);
            if (bm + m < M)
                v = *(const float4*)&A[(size_t)(bm + m) * K + k0 + kk4];
            As[kk4 + 0][m] = v.x;
            As[kk4 + 1][m] = v.y;
            As[kk4 + 2][m] = v.z;
            As[kk4 + 3][m] = v.w;
        }
        {   // B tile: 16 k x 64 n
            int kk = tid >> 4;
            int n4 = (tid & 15) * 4;
            *(float4*)&Bs[kk][n4] = *(const float4*)&W[(size_t)(k0 + kk) * N + bn + n4];
        }
        __syncthreads();
        #pragma unroll
        for (int kk = 0; kk < 16; ++kk) {
            float4 a4 = *(const float4*)&As[kk][ty * 4];
            float4 b4 = *(const float4*)&Bs[kk][tx * 4];
            float a[4] = {a4.x, a4.y, a4.z, a4.w};
            float b[4] = {b4.x, b4.y, b4.z, b4.w};
            #pragma unroll
            for (int i = 0; i < 4; ++i)
                #pragma unroll
                for (int j = 0; j < 4; ++j)
                    acc[i][j] += a[i] * b[j];
        }
        __syncthreads();
    }
    #pragma unroll
    for (int i = 0; i < 4; ++i) {
        int m = bm + ty * 4 + i;
        if (m >= M) continue;
        float v[4];
        #pragma unroll
        for (int j = 0; j < 4; ++j) {
            v[j] = acc[i][j];
            if (BIAS) v[j] += bias[bn + tx * 4 + j];
        }
        size_t base = (size_t)m * N + bn + tx * 4;
        if constexpr (OUT_BF16) {
            __hip_bfloat16* ob = (__hip_bfloat16*)out_;
            __hip_bfloat162 p0, p1;
            p0.x = __float2bfloat16(v[0]); p0.y = __float2bfloat16(v[1]);
            p1.x = __float2bfloat16(v[2]); p1.y = __float2bfloat16(v[3]);
            *(__hip_bfloat162*)&ob[base]     = p0;
            *(__hip_bfloat162*)&ob[base + 2] = p1;
        } else {
            float* of = (float*)out_;
            *(float2*)&of[base]     = make_float2(v[0], v[1]);
            *(float2*)&of[base + 2] = make_float2(v[2], v[3]);
        }
    }
}

// ---------------- CSR gather-aggregate, bf16 gather operand ----------------
// out[i] = dinv[i]*(sum_e dinv[s]*in_bf16[s] + dinv[i]*in_bf16[i]) [+bias] [relu]
// One wave per node (64 lanes); D=128 -> bf16x2 per lane, D=64 -> bf16 per lane.
// UNR-deep batches of independent row-gathers per iteration (idx/w in SGPRs).

template<int D, bool BIAS, bool RELU, bool OUT_BF16>
__global__ __launch_bounds__(256) void agg_kernel(const void* __restrict__ in_,
        const float* __restrict__ bias,
        const int* __restrict__ rowptr, const int* __restrict__ colidx,
        const float* __restrict__ dinv, void* __restrict__ out_, int n) {
    constexpr int VPL = D / 64;            // values per lane: 2 (D=128) or 1 (D=64)
    constexpr int UNR = (VPL == 2) ? 12 : 16;
    const int lane = (int)threadIdx.x & 63;
    const int wid  = (int)threadIdx.x >> 6;
    const int i = blockIdx.x * 4 + wid;
    if (i >= n) return;
    const float di = dinv[i];
    float acc0 = 0.f, acc1 = 0.f;
    if constexpr (VPL == 2) {
        const __hip_bfloat162* in = (const __hip_bfloat162*)in_;
        __hip_bfloat162 sv = in[(size_t)i * 64 + lane];
        acc0 = di * __bfloat162float(sv.x);
        acc1 = di * __bfloat162float(sv.y);
    } else {
        const __hip_bfloat16* in = (const __hip_bfloat16*)in_;
        acc0 = di * __bfloat162float(in[(size_t)i * 64 + lane]);
    }
    int e = rowptr[i];
    const int e1 = rowptr[i + 1];
    for (; e + UNR <= e1; e += UNR) {
        int s[UNR]; float w[UNR];
        #pragma unroll
        for (int j = 0; j < UNR; ++j) s[j] = __builtin_amdgcn_readfirstlane(colidx[e + j]);
        #pragma unroll
        for (int j = 0; j < UNR; ++j) w[j] = dinv[s[j]];
        if constexpr (VPL == 2) {
            const __hip_bfloat162* in = (const __hip_bfloat162*)in_;
            __hip_bfloat162 v[UNR];
            #pragma unroll
            for (int j = 0; j < UNR; ++j) v[j] = in[(size_t)s[j] * 64 + lane];
            #pragma unroll
            for (int j = 0; j < UNR; ++j) {
                acc0 += w[j] * __bfloat162float(v[j].x);
                acc1 += w[j] * __bfloat162float(v[j].y);
            }
        } else {
            const __hip_bfloat16* in = (const __hip_bfloat16*)in_;
            __hip_bfloat16 v[UNR];
            #pragma unroll
            for (int j = 0; j < UNR; ++j) v[j] = in[(size_t)s[j] * 64 + lane];
            #pragma unroll
            for (int j = 0; j < UNR; ++j) acc0 += w[j] * __bfloat162float(v[j]);
        }
    }
    for (; e < e1; ++e) {
        int s = __builtin_amdgcn_readfirstlane(colidx[e]);
        float w = dinv[s];
        if constexpr (VPL == 2) {
            const __hip_bfloat162* in = (const __hip_bfloat162*)in_;
            __hip_bfloat162 v = in[(size_t)s * 64 + lane];
            acc0 += w * __bfloat162float(v.x);
            acc1 += w * __bfloat162float(v.y);
        } else {
            const __hip_bfloat16* in = (const __hip_bfloat16*)in_;
            acc0 += w * __bfloat162float(in[(size_t)s * 64 + lane]);
        }
    }
    float v0 = di * acc0;
    float v1 = di * acc1;
    if constexpr (VPL == 2) {
        if (BIAS) { v0 += bias[2 * lane]; v1 += bias[2 * lane + 1]; }
        if (RELU) { v0 = fmaxf(v0, 0.f); v1 = fmaxf(v1, 0.f); }
        if constexpr (OUT_BF16) {
            __hip_bfloat162* ob = (__hip_bfloat162*)out_;
            __hip_bfloat162 p; p.x = __float2bfloat16(v0); p.y = __float2bfloat16(v1);
            ob[(size_t)i * 64 + lane] = p;
        } else {
            float2* of = (float2*)out_;
            of[(size_t)i * 64 + lane] = make_float2(v0, v1);
        }
    } else {
        if (BIAS) v0 += bias[lane];
        if (RELU) v0 = fmaxf(v0, 0.f);
        if constexpr (OUT_BF16) {
            __hip_bfloat16* ob = (__hip_bfloat16*)out_;
            ob[(size_t)i * 64 + lane] = __float2bfloat16(v0);
        } else {
            float* of = (float*)out_;
            of[(size_t)i * 64 + lane] = v0;
        }
    }
}

// ---------------- driver ----------------

extern "C" void kernel_launch(void* const* d_in, const int* in_sizes, int n_in,
                              void* d_out, int out_size, void* d_ws, size_t ws_size,
                              hipStream_t stream) {
    const float* x  = (const float*)d_in[0];
    const int*   ei = (const int*)d_in[1];
    const float* W1 = (const float*)d_in[2];
    const float* b1 = (const float*)d_in[3];
    const float* W2 = (const float*)d_in[4];
    const float* b2 = (const float*)d_in[5];
    const float* W3 = (const float*)d_in[6];
    const float* b3 = (const float*)d_in[7];

    const int IN = 128;
    const int n  = in_sizes[0] / IN;   // 50000
    const int E  = in_sizes[1] / 2;    // 800000

    char* ws = (char*)d_ws;
    size_t off = 0;
    auto alloc = [&](size_t bytes) {
        char* p = ws + off;
        off += (bytes + 255) & ~(size_t)255;
        return p;
    };
    __hip_bfloat16* hA_bf = (__hip_bfloat16*)alloc((size_t)n * 128 * 2);  // 12.8 MB (h1 pre-agg)
    float*          bufB  = (float*)alloc((size_t)n * 128 * 4);           // 25.6 MB (h1 post-agg)
    __hip_bfloat16* hC_bf = (__hip_bfloat16*)alloc((size_t)n * 64 * 2);   //  6.4 MB (h1@W2)
    __hip_bfloat16* hD_bf = (__hip_bfloat16*)alloc((size_t)n * 64 * 2);   //  6.4 MB (h2)
    float*          bufE  = (float*)alloc((size_t)n * 64 * 4);            // 12.8 MB (Agg(h2))
    int*   rowptr = (int*)  alloc(((size_t)n + 1) * sizeof(int));
    float* dinv   = (float*)alloc((size_t)n * sizeof(float));
    int*   colidx = (int*)  alloc((size_t)E * sizeof(int));               //  3.2 MB
    unsigned int* tmp = (unsigned int*)alloc((size_t)E * sizeof(unsigned int)); // 3.2 MB
    int*   hist_b = (int*)  alloc((size_t)256 * SORT_BLOCKS * sizeof(int)); // 256 KB
    int*   btot   = (int*)  alloc(256 * sizeof(int));
    int*   bstart = (int*)  alloc(257 * sizeof(int));

    const int nbucket = ceil_div(n, 256);          // 196 (<= 256)
    const int chunk   = ceil_div(E, SORT_BLOCKS);  // 3125

    // ---- CSR build: zero global atomics, 4 dispatches ----
    bucket_hist_kernel<<<SORT_BLOCKS, 256, 0, stream>>>(ei, hist_b, E, nbucket, chunk);
    row_scan_kernel<<<nbucket, 256, 0, stream>>>(hist_b, btot);
    bucket_scatter_kernel<<<SORT_BLOCKS, 256, 0, stream>>>(ei, hist_b, btot, bstart, tmp, E, nbucket, chunk);
    csr_build_kernel<<<nbucket, 256, 0, stream>>>(tmp, bstart, rowptr, dinv, colidx, n, E);

    // ---- Layer 1: h1 = relu(Agg(x @ W1) + b1)  (agg at 128, bf16 gather) ----
    dim3 g1(ceil_div(n, 64), 2);
    gemm_kernel<128, 128, false, true><<<g1, 256, 0, stream>>>(x, W1, nullptr, hA_bf, n);
    agg_kernel<128, true, true, false><<<ceil_div(n, 4), 256, 0, stream>>>(
        hA_bf, b1, rowptr, colidx, dinv, bufB, n);

    // ---- Layer 2: h2 = relu(Agg(h1 @ W2) + b2)  (transform first -> agg at 64, bf16) ----
    dim3 g2(ceil_div(n, 64), 1);
    gemm_kernel<128, 64, false, true><<<g2, 256, 0, stream>>>(bufB, W2, nullptr, hC_bf, n);
    agg_kernel<64, true, true, true><<<ceil_div(n, 4), 256, 0, stream>>>(
        hC_bf, b2, rowptr, colidx, dinv, hD_bf, n);

    // ---- Layer 3: out = Agg(h2) @ W3 + b3  (agg first at 64, bf16; Agg commutes with W) ----
    agg_kernel<64, false, false, false><<<ceil_div(n, 4), 256, 0, stream>>>(
        hD_bf, nullptr, rowptr, colidx, dinv, bufE, n);
    dim3 g3(ceil_div(n, 64), 2);
    gemm_kernel<64, 128, true, false><<<g3, 256, 0, stream>>>(bufE, W3, b3, d_out, n);
}

// Round 12
// 276.625 us; speedup vs baseline: 1.1644x; 1.1644x over previous
//
#include <hip/hip_runtime.h>
#include <hip/hip_bf16.h>

static inline int ceil_div(int a, int b) { return (a + b - 1) / b; }

// ================= Atomic-free CSR build: 2-level MSD bucket sort =================
// Bucket = dst >> 8 (nbucket = ceil(n/256) <= 256). No global atomics anywhere.
// Edges packed as u32: src (16b) | (dst & 255) << 16.   (n < 65536 required)

#define SORT_BLOCKS 256

// K0: per-block LDS histogram of coarse buckets
__global__ __launch_bounds__(256) void bucket_hist_kernel(const int* __restrict__ ei,
        int* __restrict__ hist_b, int E, int nbucket, int chunk) {
    __shared__ int h[256];
    const int t = (int)threadIdx.x;
    h[t] = 0;
    __syncthreads();
    const int b = blockIdx.x;
    const int e0 = b * chunk, e1 = min(E, e0 + chunk);
    for (int e = e0 + t; e < e1; e += 256)
        atomicAdd(&h[ei[E + e] >> 8], 1);              // LDS atomic, ~1.3 thr/ctr
    __syncthreads();
    if (t < nbucket) hist_b[t * SORT_BLOCKS + b] = h[t];
}

// K1: one block per bucket. Coalesced row load -> block scan -> in-place exclusive
// per-block bases + row total to btot.
__global__ __launch_bounds__(256) void row_scan_kernel(int* __restrict__ hist_b,
        int* __restrict__ btot) {
    const int i = blockIdx.x;            // bucket
    const int t = (int)threadIdx.x;      // block column
    int c = hist_b[i * SORT_BLOCKS + t];
    int v = c;
    const int lane = t & 63, wid = t >> 6;
    #pragma unroll
    for (int off = 1; off < 64; off <<= 1) {
        int u = __shfl_up(v, off);
        if (lane >= off) v += u;
    }
    __shared__ int wsum[4];
    if (lane == 63) wsum[wid] = v;
    __syncthreads();
    int wbase = 0;
    #pragma unroll
    for (int w = 0; w < 4; ++w) if (w < wid) wbase += wsum[w];
    v += wbase;                           // inclusive prefix over row
    hist_b[i * SORT_BLOCKS + t] = v - c;  // exclusive base for (bucket i, block t)
    if (t == 255) btot[i] = v;            // row total
}

// K2: scatter packed (src, dst&255) into bucket-grouped tmp[].
// Each block redundantly scans btot in LDS (cheap, parallel) -> bstart; block 0
// publishes bstart to global for K3. Disjoint slots per block -> no global atomics.
__global__ __launch_bounds__(256) void bucket_scatter_kernel(const int* __restrict__ ei,
        const int* __restrict__ rel_base, const int* __restrict__ btot,
        int* __restrict__ bstart, unsigned int* __restrict__ tmp,
        int E, int nbucket, int chunk) {
    __shared__ int sc[256];
    __shared__ int cur[256];
    const int t = (int)threadIdx.x;
    const int b = blockIdx.x;
    int tot = (t < nbucket) ? btot[t] : 0;
    sc[t] = tot;
    __syncthreads();
    for (int off = 1; off < 256; off <<= 1) {          // inclusive Hillis-Steele
        int v = (t >= off) ? sc[t - off] : 0;
        __syncthreads();
        sc[t] += v;
        __syncthreads();
    }
    const int my_bstart = sc[t] - tot;                 // exclusive
    if (b == 0) {
        if (t < nbucket) bstart[t] = my_bstart;
        if (t == 0) bstart[nbucket] = E;
    }
    if (t < nbucket) cur[t] = my_bstart + rel_base[t * SORT_BLOCKS + b];
    __syncthreads();
    const int e0 = b * chunk, e1 = min(E, e0 + chunk);
    for (int e = e0 + t; e < e1; e += 256) {
        int s = ei[e];
        int d = ei[E + e];
        int pos = atomicAdd(&cur[d >> 8], 1);           // LDS atomic
        tmp[pos] = (unsigned int)s | ((unsigned int)(d & 255) << 16);
    }
}

// K3: one block per bucket. LDS 256-bin histogram + scan -> rowptr/dinv/colidx.
__global__ __launch_bounds__(256) void csr_build_kernel(const unsigned int* __restrict__ tmp,
        const int* __restrict__ bucket_start, int* __restrict__ rowptr,
        float* __restrict__ dinv, int* __restrict__ colidx, int n, int E) {
    __shared__ int hist[256], sc[256], cur[256];
    const int h = blockIdx.x;
    const int t = (int)threadIdx.x;
    hist[t] = 0;
    __syncthreads();
    const int e0 = bucket_start[h], e1 = bucket_start[h + 1];
    for (int e = e0 + t; e < e1; e += 256)
        atomicAdd(&hist[(tmp[e] >> 16) & 255], 1);      // LDS atomic
    __syncthreads();
    sc[t] = hist[t];
    __syncthreads();
    for (int off = 1; off < 256; off <<= 1) {           // inclusive scan
        int v = (t >= off) ? sc[t - off] : 0;
        __syncthreads();
        sc[t] += v;
        __syncthreads();
    }
    const int excl = sc[t] - hist[t];
    const int node = h * 256 + t;
    if (node < n) {
        rowptr[node] = e0 + excl;
        dinv[node] = rsqrtf((float)(hist[t] + 1));      // +1 self-loop
    }
    if (h == 0 && t == 0) rowptr[n] = E;
    cur[t] = excl;
    __syncthreads();
    for (int e = e0 + t; e < e1; e += 256) {
        unsigned int p = tmp[e];
        int pos = e0 + atomicAdd(&cur[(p >> 16) & 255], 1);   // LDS atomic
        colidx[pos] = (int)(p & 0xFFFFu);
    }
}

// ---------------- fp32 tiled GEMM: out[M,N] = A[M,K] @ W[K,N] (+bias), fp32 or bf16 out ----

template<int K, int N, bool BIAS, bool OUT_BF16>
__global__ __launch_bounds__(256) void gemm_kernel(const float* __restrict__ A,
        const float* __restrict__ W, const float* __restrict__ bias,
        void* __restrict__ out_, int M) {
    __shared__ float As[16][68];   // [k][m], padded
    __shared__ float Bs[16][68];   // [k][n]
    const int bm = blockIdx.x * 64;
    const int bn = blockIdx.y * 64;
    const int tid = (int)threadIdx.x;
    const int tx = tid & 15;
    const int ty = tid >> 4;
    float acc[4][4] = {};
    for (int k0 = 0; k0 < K; k0 += 16) {
        {   // A tile: 64 rows x 16 k, float4-coalesced, stored transposed
            int m   = tid >> 2;
            int kk4 = (tid & 3) * 4;
            float4 v = make_float4(0.f, 0.f, 0.f, 0.f);
            if (bm + m < M)
                v = *(const float4*)&A[(size_t)(bm + m) * K + k0 + kk4];
            As[kk4 + 0][m] = v.x;
            As[kk4 + 1][m] = v.y;
            As[kk4 + 2][m] = v.z;
            As[kk4 + 3][m] = v.w;
        }
        {   // B tile: 16 k x 64 n
            int kk = tid >> 4;
            int n4 = (tid & 15) * 4;
            *(float4*)&Bs[kk][n4] = *(const float4*)&W[(size_t)(k0 + kk) * N + bn + n4];
        }
        __syncthreads();
        #pragma unroll
        for (int kk = 0; kk < 16; ++kk) {
            float4 a4 = *(const float4*)&As[kk][ty * 4];
            float4 b4 = *(const float4*)&Bs[kk][tx * 4];
            float a[4] = {a4.x, a4.y, a4.z, a4.w};
            float b[4] = {b4.x, b4.y, b4.z, b4.w};
            #pragma unroll
            for (int i = 0; i < 4; ++i)
                #pragma unroll
                for (int j = 0; j < 4; ++j)
                    acc[i][j] += a[i] * b[j];
        }
        __syncthreads();
    }
    #pragma unroll
    for (int i = 0; i < 4; ++i) {
        int m = bm + ty * 4 + i;
        if (m >= M) continue;
        float v[4];
        #pragma unroll
        for (int j = 0; j < 4; ++j) {
            v[j] = acc[i][j];
            if (BIAS) v[j] += bias[bn + tx * 4 + j];
        }
        size_t base = (size_t)m * N + bn + tx * 4;
        if constexpr (OUT_BF16) {
            __hip_bfloat16* ob = (__hip_bfloat16*)out_;
            __hip_bfloat162 p0, p1;
            p0.x = __float2bfloat16(v[0]); p0.y = __float2bfloat16(v[1]);
            p1.x = __float2bfloat16(v[2]); p1.y = __float2bfloat16(v[3]);
            *(__hip_bfloat162*)&ob[base]     = p0;
            *(__hip_bfloat162*)&ob[base + 2] = p1;
        } else {
            float* of = (float*)out_;
            *(float2*)&of[base]     = make_float2(v[0], v[1]);
            *(float2*)&of[base + 2] = make_float2(v[2], v[3]);
        }
    }
}

// ---------------- CSR gather-aggregate, bf16 gather operand ----------------
// out[i] = dinv[i]*(sum_e dinv[s]*in_bf16[s] + dinv[i]*in_bf16[i]) [+bias] [relu]
// One wave per node (64 lanes); D=128 -> bf16x2 per lane, D=64 -> bf16 per lane.
// UNR=8: validated sweet spot (R10); 16 regressed via tail-loop + scalar-batch cost (R11).

template<int D, bool BIAS, bool RELU, bool OUT_BF16>
__global__ __launch_bounds__(256) void agg_kernel(const void* __restrict__ in_,
        const float* __restrict__ bias,
        const int* __restrict__ rowptr, const int* __restrict__ colidx,
        const float* __restrict__ dinv, void* __restrict__ out_, int n) {
    constexpr int VPL = D / 64;   // values per lane: 2 (D=128) or 1 (D=64)
    const int lane = (int)threadIdx.x & 63;
    const int wid  = (int)threadIdx.x >> 6;
    const int i = blockIdx.x * 4 + wid;
    if (i >= n) return;
    const float di = dinv[i];
    float acc0 = 0.f, acc1 = 0.f;
    if constexpr (VPL == 2) {
        const __hip_bfloat162* in = (const __hip_bfloat162*)in_;
        __hip_bfloat162 sv = in[(size_t)i * 64 + lane];
        acc0 = di * __bfloat162float(sv.x);
        acc1 = di * __bfloat162float(sv.y);
    } else {
        const __hip_bfloat16* in = (const __hip_bfloat16*)in_;
        acc0 = di * __bfloat162float(in[(size_t)i * 64 + lane]);
    }
    int e = rowptr[i];
    const int e1 = rowptr[i + 1];
    for (; e + 8 <= e1; e += 8) {
        int s[8]; float w[8];
        #pragma unroll
        for (int j = 0; j < 8; ++j) s[j] = __builtin_amdgcn_readfirstlane(colidx[e + j]);
        #pragma unroll
        for (int j = 0; j < 8; ++j) w[j] = dinv[s[j]];
        if constexpr (VPL == 2) {
            const __hip_bfloat162* in = (const __hip_bfloat162*)in_;
            __hip_bfloat162 v[8];
            #pragma unroll
            for (int j = 0; j < 8; ++j) v[j] = in[(size_t)s[j] * 64 + lane];
            #pragma unroll
            for (int j = 0; j < 8; ++j) {
                acc0 += w[j] * __bfloat162float(v[j].x);
                acc1 += w[j] * __bfloat162float(v[j].y);
            }
        } else {
            const __hip_bfloat16* in = (const __hip_bfloat16*)in_;
            __hip_bfloat16 v[8];
            #pragma unroll
            for (int j = 0; j < 8; ++j) v[j] = in[(size_t)s[j] * 64 + lane];
            #pragma unroll
            for (int j = 0; j < 8; ++j) acc0 += w[j] * __bfloat162float(v[j]);
        }
    }
    for (; e < e1; ++e) {
        int s = __builtin_amdgcn_readfirstlane(colidx[e]);
        float w = dinv[s];
        if constexpr (VPL == 2) {
            const __hip_bfloat162* in = (const __hip_bfloat162*)in_;
            __hip_bfloat162 v = in[(size_t)s * 64 + lane];
            acc0 += w * __bfloat162float(v.x);
            acc1 += w * __bfloat162float(v.y);
        } else {
            const __hip_bfloat16* in = (const __hip_bfloat16*)in_;
            acc0 += w * __bfloat162float(in[(size_t)s * 64 + lane]);
        }
    }
    float v0 = di * acc0;
    float v1 = di * acc1;
    if constexpr (VPL == 2) {
        if (BIAS) { v0 += bias[2 * lane]; v1 += bias[2 * lane + 1]; }
        if (RELU) { v0 = fmaxf(v0, 0.f); v1 = fmaxf(v1, 0.f); }
        if constexpr (OUT_BF16) {
            __hip_bfloat162* ob = (__hip_bfloat162*)out_;
            __hip_bfloat162 p; p.x = __float2bfloat16(v0); p.y = __float2bfloat16(v1);
            ob[(size_t)i * 64 + lane] = p;
        } else {
            float2* of = (float2*)out_;
            of[(size_t)i * 64 + lane] = make_float2(v0, v1);
        }
    } else {
        if (BIAS) v0 += bias[lane];
        if (RELU) v0 = fmaxf(v0, 0.f);
        if constexpr (OUT_BF16) {
            __hip_bfloat16* ob = (__hip_bfloat16*)out_;
            ob[(size_t)i * 64 + lane] = __float2bfloat16(v0);
        } else {
            float* of = (float*)out_;
            of[(size_t)i * 64 + lane] = v0;
        }
    }
}

// ---------------- driver ----------------

extern "C" void kernel_launch(void* const* d_in, const int* in_sizes, int n_in,
                              void* d_out, int out_size, void* d_ws, size_t ws_size,
                              hipStream_t stream) {
    const float* x  = (const float*)d_in[0];
    const int*   ei = (const int*)d_in[1];
    const float* W1 = (const float*)d_in[2];
    const float* b1 = (const float*)d_in[3];
    const float* W2 = (const float*)d_in[4];
    const float* b2 = (const float*)d_in[5];
    const float* W3 = (const float*)d_in[6];
    const float* b3 = (const float*)d_in[7];

    const int IN = 128;
    const int n  = in_sizes[0] / IN;   // 50000
    const int E  = in_sizes[1] / 2;    // 800000

    char* ws = (char*)d_ws;
    size_t off = 0;
    auto alloc = [&](size_t bytes) {
        char* p = ws + off;
        off += (bytes + 255) & ~(size_t)255;
        return p;
    };
    __hip_bfloat16* hA_bf = (__hip_bfloat16*)alloc((size_t)n * 128 * 2);  // 12.8 MB (h1 pre-agg)
    float*          bufB  = (float*)alloc((size_t)n * 128 * 4);           // 25.6 MB (h1 post-agg)
    __hip_bfloat16* hC_bf = (__hip_bfloat16*)alloc((size_t)n * 64 * 2);   //  6.4 MB (h1@W2)
    __hip_bfloat16* hD_bf = (__hip_bfloat16*)alloc((size_t)n * 64 * 2);   //  6.4 MB (h2)
    float*          bufE  = (float*)alloc((size_t)n * 64 * 4);            // 12.8 MB (Agg(h2))
    int*   rowptr = (int*)  alloc(((size_t)n + 1) * sizeof(int));
    float* dinv   = (float*)alloc((size_t)n * sizeof(float));
    int*   colidx = (int*)  alloc((size_t)E * sizeof(int));               //  3.2 MB
    unsigned int* tmp = (unsigned int*)alloc((size_t)E * sizeof(unsigned int)); // 3.2 MB
    int*   hist_b = (int*)  alloc((size_t)256 * SORT_BLOCKS * sizeof(int)); // 256 KB
    int*   btot   = (int*)  alloc(256 * sizeof(int));
    int*   bstart = (int*)  alloc(257 * sizeof(int));

    const int nbucket = ceil_div(n, 256);          // 196 (<= 256)
    const int chunk   = ceil_div(E, SORT_BLOCKS);  // 3125

    // ---- CSR build: zero global atomics, 4 dispatches ----
    bucket_hist_kernel<<<SORT_BLOCKS, 256, 0, stream>>>(ei, hist_b, E, nbucket, chunk);
    row_scan_kernel<<<nbucket, 256, 0, stream>>>(hist_b, btot);
    bucket_scatter_kernel<<<SORT_BLOCKS, 256, 0, stream>>>(ei, hist_b, btot, bstart, tmp, E, nbucket, chunk);
    csr_build_kernel<<<nbucket, 256, 0, stream>>>(tmp, bstart, rowptr, dinv, colidx, n, E);

    // ---- Layer 1: h1 = relu(Agg(x @ W1) + b1)  (agg at 128, bf16 gather) ----
    dim3 g1(ceil_div(n, 64), 2);
    gemm_kernel<128, 128, false, true><<<g1, 256, 0, stream>>>(x, W1, nullptr, hA_bf, n);
    agg_kernel<128, true, true, false><<<ceil_div(n, 4), 256, 0, stream>>>(
        hA_bf, b1, rowptr, colidx, dinv, bufB, n);

    // ---- Layer 2: h2 = relu(Agg(h1 @ W2) + b2)  (transform first -> agg at 64, bf16) ----
    dim3 g2(ceil_div(n, 64), 1);
    gemm_kernel<128, 64, false, true><<<g2, 256, 0, stream>>>(bufB, W2, nullptr, hC_bf, n);
    agg_kernel<64, true, true, true><<<ceil_div(n, 4), 256, 0, stream>>>(
        hC_bf, b2, rowptr, colidx, dinv, hD_bf, n);

    // ---- Layer 3: out = Agg(h2) @ W3 + b3  (agg first at 64, bf16; Agg commutes with W) ----
    agg_kernel<64, false, false, false><<<ceil_div(n, 4), 256, 0, stream>>>(
        hD_bf, nullptr, rowptr, colidx, dinv, bufE, n);
    dim3 g3(ceil_div(n, 64), 2);
    gemm_kernel<64, 128, true, false><<<g3, 256, 0, stream>>>(bufE, W3, b3, d_out, n);
}

// Round 13
// 270.695 us; speedup vs baseline: 1.1899x; 1.0219x over previous
//
#include <hip/hip_runtime.h>
#include <hip/hip_bf16.h>

static inline int ceil_div(int a, int b) { return (a + b - 1) / b; }

typedef __attribute__((ext_vector_type(8))) short short8v;   // 8 bf16 = 4 VGPR
typedef __attribute__((ext_vector_type(4))) float f32x4;

__device__ inline short f2bf(float v) {                      // RNE round to bf16
    unsigned u = __builtin_bit_cast(unsigned, v);
    unsigned r = (u + 0x7FFFu + ((u >> 16) & 1u)) >> 16;
    return (short)r;
}
__device__ inline float bf2f(short s) {
    unsigned u = ((unsigned)(unsigned short)s) << 16;
    return __builtin_bit_cast(float, u);
}

// ================= Atomic-free CSR build: 2-level MSD bucket sort =================
// Bucket = dst >> 8 (nbucket = ceil(n/256) <= 256). No global atomics anywhere.
// Edges packed as u32: src (16b) | (dst & 255) << 16.   (n < 65536 required)

#define SORT_BLOCKS 256

__global__ __launch_bounds__(256) void bucket_hist_kernel(const int* __restrict__ ei,
        int* __restrict__ hist_b, int E, int nbucket, int chunk) {
    __shared__ int h[256];
    const int t = (int)threadIdx.x;
    h[t] = 0;
    __syncthreads();
    const int b = blockIdx.x;
    const int e0 = b * chunk, e1 = min(E, e0 + chunk);
    for (int e = e0 + t; e < e1; e += 256)
        atomicAdd(&h[ei[E + e] >> 8], 1);              // LDS atomic
    __syncthreads();
    if (t < nbucket) hist_b[t * SORT_BLOCKS + b] = h[t];
}

__global__ __launch_bounds__(256) void row_scan_kernel(int* __restrict__ hist_b,
        int* __restrict__ btot) {
    const int i = blockIdx.x;            // bucket
    const int t = (int)threadIdx.x;      // block column
    int c = hist_b[i * SORT_BLOCKS + t];
    int v = c;
    const int lane = t & 63, wid = t >> 6;
    #pragma unroll
    for (int off = 1; off < 64; off <<= 1) {
        int u = __shfl_up(v, off);
        if (lane >= off) v += u;
    }
    __shared__ int wsum[4];
    if (lane == 63) wsum[wid] = v;
    __syncthreads();
    int wbase = 0;
    #pragma unroll
    for (int w = 0; w < 4; ++w) if (w < wid) wbase += wsum[w];
    v += wbase;                           // inclusive prefix over row
    hist_b[i * SORT_BLOCKS + t] = v - c;  // exclusive base for (bucket i, block t)
    if (t == 255) btot[i] = v;            // row total
}

__global__ __launch_bounds__(256) void bucket_scatter_kernel(const int* __restrict__ ei,
        const int* __restrict__ rel_base, const int* __restrict__ btot,
        int* __restrict__ bstart, unsigned int* __restrict__ tmp,
        int E, int nbucket, int chunk) {
    __shared__ int sc[256];
    __shared__ int cur[256];
    const int t = (int)threadIdx.x;
    const int b = blockIdx.x;
    int tot = (t < nbucket) ? btot[t] : 0;
    sc[t] = tot;
    __syncthreads();
    for (int off = 1; off < 256; off <<= 1) {          // inclusive Hillis-Steele
        int v = (t >= off) ? sc[t - off] : 0;
        __syncthreads();
        sc[t] += v;
        __syncthreads();
    }
    const int my_bstart = sc[t] - tot;                 // exclusive
    if (b == 0) {
        if (t < nbucket) bstart[t] = my_bstart;
        if (t == 0) bstart[nbucket] = E;
    }
    if (t < nbucket) cur[t] = my_bstart + rel_base[t * SORT_BLOCKS + b];
    __syncthreads();
    const int e0 = b * chunk, e1 = min(E, e0 + chunk);
    for (int e = e0 + t; e < e1; e += 256) {
        int s = ei[e];
        int d = ei[E + e];
        int pos = atomicAdd(&cur[d >> 8], 1);           // LDS atomic
        tmp[pos] = (unsigned int)s | ((unsigned int)(d & 255) << 16);
    }
}

__global__ __launch_bounds__(256) void csr_build_kernel(const unsigned int* __restrict__ tmp,
        const int* __restrict__ bucket_start, int* __restrict__ rowptr,
        float* __restrict__ dinv, int* __restrict__ colidx, int n, int E) {
    __shared__ int hist[256], sc[256], cur[256];
    const int h = blockIdx.x;
    const int t = (int)threadIdx.x;
    hist[t] = 0;
    __syncthreads();
    const int e0 = bucket_start[h], e1 = bucket_start[h + 1];
    for (int e = e0 + t; e < e1; e += 256)
        atomicAdd(&hist[(tmp[e] >> 16) & 255], 1);      // LDS atomic
    __syncthreads();
    sc[t] = hist[t];
    __syncthreads();
    for (int off = 1; off < 256; off <<= 1) {           // inclusive scan
        int v = (t >= off) ? sc[t - off] : 0;
        __syncthreads();
        sc[t] += v;
        __syncthreads();
    }
    const int excl = sc[t] - hist[t];
    const int node = h * 256 + t;
    if (node < n) {
        rowptr[node] = e0 + excl;
        dinv[node] = rsqrtf((float)(hist[t] + 1));      // +1 self-loop
    }
    if (h == 0 && t == 0) rowptr[n] = E;
    cur[t] = excl;
    __syncthreads();
    for (int e = e0 + t; e < e1; e += 256) {
        unsigned int p = tmp[e];
        int pos = e0 + atomicAdd(&cur[(p >> 16) & 255], 1);   // LDS atomic
        colidx[pos] = (int)(p & 0xFFFFu);
    }
}

// ---------------- MFMA GEMM (3-term split bf16 ~= fp32): out[M,N] = A @ W (+bias) ----------------
// Block tile 64x64, 4 waves (2x2 of 32x32), K-chunks of 32.
// A,B staged in LDS as hi/lo bf16 with XOR swizzle (byte ^= (row&7)<<4) -> conflict-free b128.
// A frag: lane l -> row = l&15, k = (l>>4)*8..+7.  B frag: col = l&15, same k (LDS holds B^T).
// C/D: col = lane&15, row = (lane>>4)*4 + reg  [m89-verified].

__device__ inline int swz(int r, int k) {      // short-index into [64][32] bf16 tile
    int byte = r * 64 + k * 2;
    byte ^= (r & 7) << 4;
    return byte >> 1;
}

template<int K, int N, bool BIAS, bool OUT_BF16>
__global__ __launch_bounds__(256) void gemm_mfma_kernel(const float* __restrict__ A,
        const float* __restrict__ W, const float* __restrict__ bias,
        void* __restrict__ out_, int M) {
    __shared__ short Ah_s[2048], Al_s[2048], Bh_s[2048], Bl_s[2048];  // 4x 4KB
    const int tid  = (int)threadIdx.x;
    const int lane = tid & 63;
    const int wid  = tid >> 6;
    const int bm = blockIdx.x * 64;
    const int bn = blockIdx.y * 64;
    const int wr = (wid >> 1) * 32;     // wave row offset in tile
    const int wc = (wid & 1) * 32;      // wave col offset

    f32x4 acc00 = {0.f,0.f,0.f,0.f}, acc01 = {0.f,0.f,0.f,0.f};
    f32x4 acc10 = {0.f,0.f,0.f,0.f}, acc11 = {0.f,0.f,0.f,0.f};

    const int a_row = tid >> 2;                 // staging A: 64 rows x 32 k
    const int a_k0  = (tid & 3) * 8;
    const int b_k   = tid >> 3;                 // staging B: 32 k x 64 cols
    const int b_c0  = (tid & 7) * 8;

    for (int kc = 0; kc < K; kc += 32) {
        {   // ---- stage A (hi/lo split) ----
            float v[8] = {0.f,0.f,0.f,0.f,0.f,0.f,0.f,0.f};
            int grow = bm + a_row;
            if (grow < M) {
                float4 p0 = *(const float4*)&A[(size_t)grow * K + kc + a_k0];
                float4 p1 = *(const float4*)&A[(size_t)grow * K + kc + a_k0 + 4];
                v[0]=p0.x; v[1]=p0.y; v[2]=p0.z; v[3]=p0.w;
                v[4]=p1.x; v[5]=p1.y; v[6]=p1.z; v[7]=p1.w;
            }
            short8v hv, lv;
            #pragma unroll
            for (int j = 0; j < 8; ++j) {
                short h = f2bf(v[j]);
                hv[j] = h;
                lv[j] = f2bf(v[j] - bf2f(h));
            }
            *(short8v*)&Ah_s[swz(a_row, a_k0)] = hv;
            *(short8v*)&Al_s[swz(a_row, a_k0)] = lv;
        }
        {   // ---- stage B transposed: LDS[col][k] ----
            float4 p0 = *(const float4*)&W[(size_t)(kc + b_k) * N + bn + b_c0];
            float4 p1 = *(const float4*)&W[(size_t)(kc + b_k) * N + bn + b_c0 + 4];
            float v[8] = {p0.x,p0.y,p0.z,p0.w,p1.x,p1.y,p1.z,p1.w};
            #pragma unroll
            for (int j = 0; j < 8; ++j) {
                short h = f2bf(v[j]);
                Bh_s[swz(b_c0 + j, b_k)] = h;
                Bl_s[swz(b_c0 + j, b_k)] = f2bf(v[j] - bf2f(h));
            }
        }
        __syncthreads();
        {   // ---- fragment loads + 12 MFMA ----
            const int fr = lane & 15;
            const int kb = (lane >> 4) * 8;
            short8v ah0 = *(const short8v*)&Ah_s[swz(wr +  0 + fr, kb)];
            short8v ah1 = *(const short8v*)&Ah_s[swz(wr + 16 + fr, kb)];
            short8v al0 = *(const short8v*)&Al_s[swz(wr +  0 + fr, kb)];
            short8v al1 = *(const short8v*)&Al_s[swz(wr + 16 + fr, kb)];
            short8v bh0 = *(const short8v*)&Bh_s[swz(wc +  0 + fr, kb)];
            short8v bh1 = *(const short8v*)&Bh_s[swz(wc + 16 + fr, kb)];
            short8v bl0 = *(const short8v*)&Bl_s[swz(wc +  0 + fr, kb)];
            short8v bl1 = *(const short8v*)&Bl_s[swz(wc + 16 + fr, kb)];
            acc00 = __builtin_amdgcn_mfma_f32_16x16x32_bf16(ah0, bh0, acc00, 0, 0, 0);
            acc00 = __builtin_amdgcn_mfma_f32_16x16x32_bf16(al0, bh0, acc00, 0, 0, 0);
            acc00 = __builtin_amdgcn_mfma_f32_16x16x32_bf16(ah0, bl0, acc00, 0, 0, 0);
            acc01 = __builtin_amdgcn_mfma_f32_16x16x32_bf16(ah0, bh1, acc01, 0, 0, 0);
            acc01 = __builtin_amdgcn_mfma_f32_16x16x32_bf16(al0, bh1, acc01, 0, 0, 0);
            acc01 = __builtin_amdgcn_mfma_f32_16x16x32_bf16(ah0, bl1, acc01, 0, 0, 0);
            acc10 = __builtin_amdgcn_mfma_f32_16x16x32_bf16(ah1, bh0, acc10, 0, 0, 0);
            acc10 = __builtin_amdgcn_mfma_f32_16x16x32_bf16(al1, bh0, acc10, 0, 0, 0);
            acc10 = __builtin_amdgcn_mfma_f32_16x16x32_bf16(ah1, bl0, acc10, 0, 0, 0);
            acc11 = __builtin_amdgcn_mfma_f32_16x16x32_bf16(ah1, bh1, acc11, 0, 0, 0);
            acc11 = __builtin_amdgcn_mfma_f32_16x16x32_bf16(al1, bh1, acc11, 0, 0, 0);
            acc11 = __builtin_amdgcn_mfma_f32_16x16x32_bf16(ah1, bl1, acc11, 0, 0, 0);
        }
        __syncthreads();
    }

    // ---- epilogue: C/D col=lane&15, row=(lane>>4)*4+r ----
    const int c0 = lane & 15;
    const int r0 = (lane >> 4) * 4;
    #pragma unroll
    for (int fi = 0; fi < 2; ++fi) {
        #pragma unroll
        for (int fj = 0; fj < 2; ++fj) {
            f32x4 a = (fi == 0) ? ((fj == 0) ? acc00 : acc01)
                                : ((fj == 0) ? acc10 : acc11);
            #pragma unroll
            for (int r = 0; r < 4; ++r) {
                int grow = bm + wr + fi * 16 + r0 + r;
                int gcol = bn + wc + fj * 16 + c0;
                if (grow < M) {
                    float val = a[r];
                    if (BIAS) val += bias[gcol];
                    if constexpr (OUT_BF16) {
                        ((__hip_bfloat16*)out_)[(size_t)grow * N + gcol] = __float2bfloat16(val);
                    } else {
                        ((float*)out_)[(size_t)grow * N + gcol] = val;
                    }
                }
            }
        }
    }
}

// ---------------- CSR gather-aggregate, bf16 gather operand ----------------
// out[i] = dinv[i]*(sum_e dinv[s]*in_bf16[s] + dinv[i]*in_bf16[i]) [+bias] [relu]
// One wave per node (64 lanes); D=128 -> bf16x2 per lane, D=64 -> bf16 per lane.
// UNR=8: validated sweet spot (R10); 16 regressed (R11).

template<int D, bool BIAS, bool RELU, bool OUT_BF16>
__global__ __launch_bounds__(256) void agg_kernel(const void* __restrict__ in_,
        const float* __restrict__ bias,
        const int* __restrict__ rowptr, const int* __restrict__ colidx,
        const float* __restrict__ dinv, void* __restrict__ out_, int n) {
    constexpr int VPL = D / 64;   // values per lane: 2 (D=128) or 1 (D=64)
    const int lane = (int)threadIdx.x & 63;
    const int wid  = (int)threadIdx.x >> 6;
    const int i = blockIdx.x * 4 + wid;
    if (i >= n) return;
    const float di = dinv[i];
    float acc0 = 0.f, acc1 = 0.f;
    if constexpr (VPL == 2) {
        const __hip_bfloat162* in = (const __hip_bfloat162*)in_;
        __hip_bfloat162 sv = in[(size_t)i * 64 + lane];
        acc0 = di * __bfloat162float(sv.x);
        acc1 = di * __bfloat162float(sv.y);
    } else {
        const __hip_bfloat16* in = (const __hip_bfloat16*)in_;
        acc0 = di * __bfloat162float(in[(size_t)i * 64 + lane]);
    }
    int e = rowptr[i];
    const int e1 = rowptr[i + 1];
    for (; e + 8 <= e1; e += 8) {
        int s[8]; float w[8];
        #pragma unroll
        for (int j = 0; j < 8; ++j) s[j] = __builtin_amdgcn_readfirstlane(colidx[e + j]);
        #pragma unroll
        for (int j = 0; j < 8; ++j) w[j] = dinv[s[j]];
        if constexpr (VPL == 2) {
            const __hip_bfloat162* in = (const __hip_bfloat162*)in_;
            __hip_bfloat162 v[8];
            #pragma unroll
            for (int j = 0; j < 8; ++j) v[j] = in[(size_t)s[j] * 64 + lane];
            #pragma unroll
            for (int j = 0; j < 8; ++j) {
                acc0 += w[j] * __bfloat162float(v[j].x);
                acc1 += w[j] * __bfloat162float(v[j].y);
            }
        } else {
            const __hip_bfloat16* in = (const __hip_bfloat16*)in_;
            __hip_bfloat16 v[8];
            #pragma unroll
            for (int j = 0; j < 8; ++j) v[j] = in[(size_t)s[j] * 64 + lane];
            #pragma unroll
            for (int j = 0; j < 8; ++j) acc0 += w[j] * __bfloat162float(v[j]);
        }
    }
    for (; e < e1; ++e) {
        int s = __builtin_amdgcn_readfirstlane(colidx[e]);
        float w = dinv[s];
        if constexpr (VPL == 2) {
            const __hip_bfloat162* in = (const __hip_bfloat162*)in_;
            __hip_bfloat162 v = in[(size_t)s * 64 + lane];
            acc0 += w * __bfloat162float(v.x);
            acc1 += w * __bfloat162float(v.y);
        } else {
            const __hip_bfloat16* in = (const __hip_bfloat16*)in_;
            acc0 += w * __bfloat162float(in[(size_t)s * 64 + lane]);
        }
    }
    float v0 = di * acc0;
    float v1 = di * acc1;
    if constexpr (VPL == 2) {
        if (BIAS) { v0 += bias[2 * lane]; v1 += bias[2 * lane + 1]; }
        if (RELU) { v0 = fmaxf(v0, 0.f); v1 = fmaxf(v1, 0.f); }
        if constexpr (OUT_BF16) {
            __hip_bfloat162* ob = (__hip_bfloat162*)out_;
            __hip_bfloat162 p; p.x = __float2bfloat16(v0); p.y = __float2bfloat16(v1);
            ob[(size_t)i * 64 + lane] = p;
        } else {
            float2* of = (float2*)out_;
            of[(size_t)i * 64 + lane] = make_float2(v0, v1);
        }
    } else {
        if (BIAS) v0 += bias[lane];
        if (RELU) v0 = fmaxf(v0, 0.f);
        if constexpr (OUT_BF16) {
            __hip_bfloat16* ob = (__hip_bfloat16*)out_;
            ob[(size_t)i * 64 + lane] = __float2bfloat16(v0);
        } else {
            float* of = (float*)out_;
            of[(size_t)i * 64 + lane] = v0;
        }
    }
}

// ---------------- driver ----------------

extern "C" void kernel_launch(void* const* d_in, const int* in_sizes, int n_in,
                              void* d_out, int out_size, void* d_ws, size_t ws_size,
                              hipStream_t stream) {
    const float* x  = (const float*)d_in[0];
    const int*   ei = (const int*)d_in[1];
    const float* W1 = (const float*)d_in[2];
    const float* b1 = (const float*)d_in[3];
    const float* W2 = (const float*)d_in[4];
    const float* b2 = (const float*)d_in[5];
    const float* W3 = (const float*)d_in[6];
    const float* b3 = (const float*)d_in[7];

    const int IN = 128;
    const int n  = in_sizes[0] / IN;   // 50000
    const int E  = in_sizes[1] / 2;    // 800000

    char* ws = (char*)d_ws;
    size_t off = 0;
    auto alloc = [&](size_t bytes) {
        char* p = ws + off;
        off += (bytes + 255) & ~(size_t)255;
        return p;
    };
    __hip_bfloat16* hA_bf = (__hip_bfloat16*)alloc((size_t)n * 128 * 2);  // 12.8 MB (h1 pre-agg)
    float*          bufB  = (float*)alloc((size_t)n * 128 * 4);           // 25.6 MB (h1 post-agg)
    __hip_bfloat16* hC_bf = (__hip_bfloat16*)alloc((size_t)n * 64 * 2);   //  6.4 MB (h1@W2)
    __hip_bfloat16* hD_bf = (__hip_bfloat16*)alloc((size_t)n * 64 * 2);   //  6.4 MB (h2)
    float*          bufE  = (float*)alloc((size_t)n * 64 * 4);            // 12.8 MB (Agg(h2))
    int*   rowptr = (int*)  alloc(((size_t)n + 1) * sizeof(int));
    float* dinv   = (float*)alloc((size_t)n * sizeof(float));
    int*   colidx = (int*)  alloc((size_t)E * sizeof(int));               //  3.2 MB
    unsigned int* tmp = (unsigned int*)alloc((size_t)E * sizeof(unsigned int)); // 3.2 MB
    int*   hist_b = (int*)  alloc((size_t)256 * SORT_BLOCKS * sizeof(int)); // 256 KB
    int*   btot   = (int*)  alloc(256 * sizeof(int));
    int*   bstart = (int*)  alloc(257 * sizeof(int));

    const int nbucket = ceil_div(n, 256);          // 196 (<= 256)
    const int chunk   = ceil_div(E, SORT_BLOCKS);  // 3125

    // ---- CSR build: zero global atomics, 4 dispatches ----
    bucket_hist_kernel<<<SORT_BLOCKS, 256, 0, stream>>>(ei, hist_b, E, nbucket, chunk);
    row_scan_kernel<<<nbucket, 256, 0, stream>>>(hist_b, btot);
    bucket_scatter_kernel<<<SORT_BLOCKS, 256, 0, stream>>>(ei, hist_b, btot, bstart, tmp, E, nbucket, chunk);
    csr_build_kernel<<<nbucket, 256, 0, stream>>>(tmp, bstart, rowptr, dinv, colidx, n, E);

    // ---- Layer 1: h1 = relu(Agg(x @ W1) + b1)  (agg at 128, bf16 gather) ----
    dim3 g1(ceil_div(n, 64), 2);
    gemm_mfma_kernel<128, 128, false, true><<<g1, 256, 0, stream>>>(x, W1, nullptr, hA_bf, n);
    agg_kernel<128, true, true, false><<<ceil_div(n, 4), 256, 0, stream>>>(
        hA_bf, b1, rowptr, colidx, dinv, bufB, n);

    // ---- Layer 2: h2 = relu(Agg(h1 @ W2) + b2)  (transform first -> agg at 64, bf16) ----
    dim3 g2(ceil_div(n, 64), 1);
    gemm_mfma_kernel<128, 64, false, true><<<g2, 256, 0, stream>>>(bufB, W2, nullptr, hC_bf, n);
    agg_kernel<64, true, true, true><<<ceil_div(n, 4), 256, 0, stream>>>(
        hC_bf, b2, rowptr, colidx, dinv, hD_bf, n);

    // ---- Layer 3: out = Agg(h2) @ W3 + b3  (agg first at 64, bf16; Agg commutes with W) ----
    agg_kernel<64, false, false, false><<<ceil_div(n, 4), 256, 0, stream>>>(
        hD_bf, nullptr, rowptr, colidx, dinv, bufE, n);
    dim3 g3(ceil_div(n, 64), 2);
    gemm_mfma_kernel<64, 128, true, false><<<g3, 256, 0, stream>>>(bufE, W3, b3, d_out, n);
}

// Round 14
// 265.078 us; speedup vs baseline: 1.2151x; 1.0212x over previous
//
#include <hip/hip_runtime.h>
#include <hip/hip_bf16.h>

static inline int ceil_div(int a, int b) { return (a + b - 1) / b; }

typedef __attribute__((ext_vector_type(8))) short short8v;   // 8 bf16 = 4 VGPR
typedef __attribute__((ext_vector_type(4))) float f32x4;

__device__ inline short f2bf(float v) {                      // RNE round to bf16
    unsigned u = __builtin_bit_cast(unsigned, v);
    unsigned r = (u + 0x7FFFu + ((u >> 16) & 1u)) >> 16;
    return (short)r;
}
__device__ inline float bf2f(short s) {
    unsigned u = ((unsigned)(unsigned short)s) << 16;
    return __builtin_bit_cast(float, u);
}

// ================= Atomic-free CSR build: 2-level MSD bucket sort =================
// Bucket = dst >> 8 (nbucket = ceil(n/256) <= 256). No global atomics anywhere.
// Edges packed as u32: src (16b) | (dst & 255) << 16.   (n < 65536 required)

#define SORT_BLOCKS 256

__global__ __launch_bounds__(256) void row_scan_kernel(int* __restrict__ hist_b,
        int* __restrict__ btot) {
    const int i = blockIdx.x;            // bucket
    const int t = (int)threadIdx.x;      // block column
    int c = hist_b[i * SORT_BLOCKS + t];
    int v = c;
    const int lane = t & 63, wid = t >> 6;
    #pragma unroll
    for (int off = 1; off < 64; off <<= 1) {
        int u = __shfl_up(v, off);
        if (lane >= off) v += u;
    }
    __shared__ int wsum[4];
    if (lane == 63) wsum[wid] = v;
    __syncthreads();
    int wbase = 0;
    #pragma unroll
    for (int w = 0; w < 4; ++w) if (w < wid) wbase += wsum[w];
    v += wbase;                           // inclusive prefix over row
    hist_b[i * SORT_BLOCKS + t] = v - c;  // exclusive base for (bucket i, block t)
    if (t == 255) btot[i] = v;            // row total
}

__global__ __launch_bounds__(256) void bucket_scatter_kernel(const int* __restrict__ ei,
        const int* __restrict__ rel_base, const int* __restrict__ btot,
        int* __restrict__ bstart, unsigned int* __restrict__ tmp,
        int E, int nbucket, int chunk) {
    __shared__ int sc[256];
    __shared__ int cur[256];
    const int t = (int)threadIdx.x;
    const int b = blockIdx.x;
    int tot = (t < nbucket) ? btot[t] : 0;
    sc[t] = tot;
    __syncthreads();
    for (int off = 1; off < 256; off <<= 1) {          // inclusive Hillis-Steele
        int v = (t >= off) ? sc[t - off] : 0;
        __syncthreads();
        sc[t] += v;
        __syncthreads();
    }
    const int my_bstart = sc[t] - tot;                 // exclusive
    if (b == 0) {
        if (t < nbucket) bstart[t] = my_bstart;
        if (t == 0) bstart[nbucket] = E;
    }
    if (t < nbucket) cur[t] = my_bstart + rel_base[t * SORT_BLOCKS + b];
    __syncthreads();
    const int e0 = b * chunk, e1 = min(E, e0 + chunk);
    for (int e = e0 + t; e < e1; e += 256) {
        int s = ei[e];
        int d = ei[E + e];
        int pos = atomicAdd(&cur[d >> 8], 1);           // LDS atomic
        tmp[pos] = (unsigned int)s | ((unsigned int)(d & 255) << 16);
    }
}

__global__ __launch_bounds__(256) void csr_build_kernel(const unsigned int* __restrict__ tmp,
        const int* __restrict__ bucket_start, int* __restrict__ rowptr,
        float* __restrict__ dinv, int* __restrict__ colidx, int n, int E) {
    __shared__ int hist[256], sc[256], cur[256];
    const int h = blockIdx.x;
    const int t = (int)threadIdx.x;
    hist[t] = 0;
    __syncthreads();
    const int e0 = bucket_start[h], e1 = bucket_start[h + 1];
    for (int e = e0 + t; e < e1; e += 256)
        atomicAdd(&hist[(tmp[e] >> 16) & 255], 1);      // LDS atomic
    __syncthreads();
    sc[t] = hist[t];
    __syncthreads();
    for (int off = 1; off < 256; off <<= 1) {           // inclusive scan
        int v = (t >= off) ? sc[t - off] : 0;
        __syncthreads();
        sc[t] += v;
        __syncthreads();
    }
    const int excl = sc[t] - hist[t];
    const int node = h * 256 + t;
    if (node < n) {
        rowptr[node] = e0 + excl;
        dinv[node] = rsqrtf((float)(hist[t] + 1));      // +1 self-loop
    }
    if (h == 0 && t == 0) rowptr[n] = E;
    cur[t] = excl;
    __syncthreads();
    for (int e = e0 + t; e < e1; e += 256) {
        unsigned int p = tmp[e];
        int pos = e0 + atomicAdd(&cur[(p >> 16) & 255], 1);   // LDS atomic
        colidx[pos] = (int)(p & 0xFFFFu);
    }
}

// ---------------- MFMA GEMM body (3-term split bf16 ~= fp32) ----------------
// Block tile 64x64, 4 waves (2x2 of 32x32), K-chunks of 32. XOR-swizzled LDS.
// C/D: col=lane&15, row=(lane>>4)*4+reg [m89-verified, R13-validated on HW].

__device__ inline int swz(int r, int k) {      // short-index into [64][32] bf16 tile
    int byte = r * 64 + k * 2;
    byte ^= (r & 7) << 4;
    return byte >> 1;
}

template<int K, int N, bool BIAS, bool OUT_BF16>
__device__ void gemm_mfma_body(const float* __restrict__ A, const float* __restrict__ W,
        const float* __restrict__ bias, void* __restrict__ out_, int M, int bm, int bn) {
    __shared__ short Ah_s[2048], Al_s[2048], Bh_s[2048], Bl_s[2048];  // 4x 4KB
    const int tid  = (int)threadIdx.x;
    const int lane = tid & 63;
    const int wid  = tid >> 6;
    const int wr = (wid >> 1) * 32;     // wave row offset in tile
    const int wc = (wid & 1) * 32;      // wave col offset

    f32x4 acc00 = {0.f,0.f,0.f,0.f}, acc01 = {0.f,0.f,0.f,0.f};
    f32x4 acc10 = {0.f,0.f,0.f,0.f}, acc11 = {0.f,0.f,0.f,0.f};

    const int a_row = tid >> 2;                 // staging A: 64 rows x 32 k
    const int a_k0  = (tid & 3) * 8;
    const int b_k   = tid >> 3;                 // staging B: 32 k x 64 cols
    const int b_c0  = (tid & 7) * 8;

    for (int kc = 0; kc < K; kc += 32) {
        {   // ---- stage A (hi/lo split) ----
            float v[8] = {0.f,0.f,0.f,0.f,0.f,0.f,0.f,0.f};
            int grow = bm + a_row;
            if (grow < M) {
                float4 p0 = *(const float4*)&A[(size_t)grow * K + kc + a_k0];
                float4 p1 = *(const float4*)&A[(size_t)grow * K + kc + a_k0 + 4];
                v[0]=p0.x; v[1]=p0.y; v[2]=p0.z; v[3]=p0.w;
                v[4]=p1.x; v[5]=p1.y; v[6]=p1.z; v[7]=p1.w;
            }
            short8v hv, lv;
            #pragma unroll
            for (int j = 0; j < 8; ++j) {
                short h = f2bf(v[j]);
                hv[j] = h;
                lv[j] = f2bf(v[j] - bf2f(h));
            }
            *(short8v*)&Ah_s[swz(a_row, a_k0)] = hv;
            *(short8v*)&Al_s[swz(a_row, a_k0)] = lv;
        }
        {   // ---- stage B transposed: LDS[col][k] ----
            float4 p0 = *(const float4*)&W[(size_t)(kc + b_k) * N + bn + b_c0];
            float4 p1 = *(const float4*)&W[(size_t)(kc + b_k) * N + bn + b_c0 + 4];
            float v[8] = {p0.x,p0.y,p0.z,p0.w,p1.x,p1.y,p1.z,p1.w};
            #pragma unroll
            for (int j = 0; j < 8; ++j) {
                short h = f2bf(v[j]);
                Bh_s[swz(b_c0 + j, b_k)] = h;
                Bl_s[swz(b_c0 + j, b_k)] = f2bf(v[j] - bf2f(h));
            }
        }
        __syncthreads();
        {   // ---- fragment loads + 12 MFMA ----
            const int fr = lane & 15;
            const int kb = (lane >> 4) * 8;
            short8v ah0 = *(const short8v*)&Ah_s[swz(wr +  0 + fr, kb)];
            short8v ah1 = *(const short8v*)&Ah_s[swz(wr + 16 + fr, kb)];
            short8v al0 = *(const short8v*)&Al_s[swz(wr +  0 + fr, kb)];
            short8v al1 = *(const short8v*)&Al_s[swz(wr + 16 + fr, kb)];
            short8v bh0 = *(const short8v*)&Bh_s[swz(wc +  0 + fr, kb)];
            short8v bh1 = *(const short8v*)&Bh_s[swz(wc + 16 + fr, kb)];
            short8v bl0 = *(const short8v*)&Bl_s[swz(wc +  0 + fr, kb)];
            short8v bl1 = *(const short8v*)&Bl_s[swz(wc + 16 + fr, kb)];
            acc00 = __builtin_amdgcn_mfma_f32_16x16x32_bf16(ah0, bh0, acc00, 0, 0, 0);
            acc00 = __builtin_amdgcn_mfma_f32_16x16x32_bf16(al0, bh0, acc00, 0, 0, 0);
            acc00 = __builtin_amdgcn_mfma_f32_16x16x32_bf16(ah0, bl0, acc00, 0, 0, 0);
            acc01 = __builtin_amdgcn_mfma_f32_16x16x32_bf16(ah0, bh1, acc01, 0, 0, 0);
            acc01 = __builtin_amdgcn_mfma_f32_16x16x32_bf16(al0, bh1, acc01, 0, 0, 0);
            acc01 = __builtin_amdgcn_mfma_f32_16x16x32_bf16(ah0, bl1, acc01, 0, 0, 0);
            acc10 = __builtin_amdgcn_mfma_f32_16x16x32_bf16(ah1, bh0, acc10, 0, 0, 0);
            acc10 = __builtin_amdgcn_mfma_f32_16x16x32_bf16(al1, bh0, acc10, 0, 0, 0);
            acc10 = __builtin_amdgcn_mfma_f32_16x16x32_bf16(ah1, bl0, acc10, 0, 0, 0);
            acc11 = __builtin_amdgcn_mfma_f32_16x16x32_bf16(ah1, bh1, acc11, 0, 0, 0);
            acc11 = __builtin_amdgcn_mfma_f32_16x16x32_bf16(al1, bh1, acc11, 0, 0, 0);
            acc11 = __builtin_amdgcn_mfma_f32_16x16x32_bf16(ah1, bl1, acc11, 0, 0, 0);
        }
        __syncthreads();
    }

    // ---- epilogue ----
    const int c0 = lane & 15;
    const int r0 = (lane >> 4) * 4;
    #pragma unroll
    for (int fi = 0; fi < 2; ++fi) {
        #pragma unroll
        for (int fj = 0; fj < 2; ++fj) {
            f32x4 a = (fi == 0) ? ((fj == 0) ? acc00 : acc01)
                                : ((fj == 0) ? acc10 : acc11);
            #pragma unroll
            for (int r = 0; r < 4; ++r) {
                int grow = bm + wr + fi * 16 + r0 + r;
                int gcol = bn + wc + fj * 16 + c0;
                if (grow < M) {
                    float val = a[r];
                    if (BIAS) val += bias[gcol];
                    if constexpr (OUT_BF16) {
                        ((__hip_bfloat16*)out_)[(size_t)grow * N + gcol] = __float2bfloat16(val);
                    } else {
                        ((float*)out_)[(size_t)grow * N + gcol] = val;
                    }
                }
            }
        }
    }
}

template<int K, int N, bool BIAS, bool OUT_BF16>
__global__ __launch_bounds__(256) void gemm_mfma_kernel(const float* __restrict__ A,
        const float* __restrict__ W, const float* __restrict__ bias,
        void* __restrict__ out_, int M) {
    gemm_mfma_body<K, N, BIAS, OUT_BF16>(A, W, bias, out_, M,
                                         blockIdx.x * 64, blockIdx.y * 64);
}

// Fused: blocks [0,SORT_BLOCKS) do the CSR coarse histogram; the rest do gemm1.
// The two are fully independent (ei vs x/W1) -> overlap, one dispatch gap saved.
template<int K, int N, bool OUT_BF16>
__global__ __launch_bounds__(256) void hist_gemm_kernel(const int* __restrict__ ei,
        int* __restrict__ hist_b, int E, int nbucket, int chunk,
        const float* __restrict__ A, const float* __restrict__ W,
        void* __restrict__ out_, int M) {
    if (blockIdx.x < SORT_BLOCKS) {
        __shared__ int h[256];
        const int t = (int)threadIdx.x;
        h[t] = 0;
        __syncthreads();
        const int b = blockIdx.x;
        const int e0 = b * chunk, e1 = min(E, e0 + chunk);
        for (int e = e0 + t; e < e1; e += 256)
            atomicAdd(&h[ei[E + e] >> 8], 1);          // LDS atomic
        __syncthreads();
        if (t < nbucket) hist_b[t * SORT_BLOCKS + b] = h[t];
    } else {
        const int bid = (int)blockIdx.x - SORT_BLOCKS;
        constexpr int TN = N / 64;
        gemm_mfma_body<K, N, false, OUT_BF16>(A, W, nullptr, out_, M,
                                              (bid / TN) * 64, (bid % TN) * 64);
    }
}

// ---------------- CSR gather-aggregate, bf16 gather operand ----------------
// D=128: one wave per node, wave-uniform edge loop, UNR=8 (R10-validated).
// D=64 : DUAL-EDGE per wave — lanes 0-31 even edges, 32-63 odd edges (each lane
//        2 cols via bf16x2); 16 edges in flight/wave; __shfl_xor(32) combine.

template<int D, bool BIAS, bool RELU, bool OUT_BF16>
__global__ __launch_bounds__(256) void agg_kernel(const void* __restrict__ in_,
        const float* __restrict__ bias,
        const int* __restrict__ rowptr, const int* __restrict__ colidx,
        const float* __restrict__ dinv, void* __restrict__ out_, int n) {
    constexpr int VPL = D / 64;
    const int lane = (int)threadIdx.x & 63;
    const int wid  = (int)threadIdx.x >> 6;
    const int i = blockIdx.x * 4 + wid;
    if (i >= n) return;
    const float di = dinv[i];

    if constexpr (VPL == 2) {
        const __hip_bfloat162* in = (const __hip_bfloat162*)in_;
        __hip_bfloat162 sv = in[(size_t)i * 64 + lane];
        float acc0 = di * __bfloat162float(sv.x);
        float acc1 = di * __bfloat162float(sv.y);
        int e = rowptr[i];
        const int e1 = rowptr[i + 1];
        for (; e + 8 <= e1; e += 8) {
            int s[8]; float w[8];
            #pragma unroll
            for (int j = 0; j < 8; ++j) s[j] = __builtin_amdgcn_readfirstlane(colidx[e + j]);
            #pragma unroll
            for (int j = 0; j < 8; ++j) w[j] = dinv[s[j]];
            __hip_bfloat162 v[8];
            #pragma unroll
            for (int j = 0; j < 8; ++j) v[j] = in[(size_t)s[j] * 64 + lane];
            #pragma unroll
            for (int j = 0; j < 8; ++j) {
                acc0 += w[j] * __bfloat162float(v[j].x);
                acc1 += w[j] * __bfloat162float(v[j].y);
            }
        }
        for (; e < e1; ++e) {
            int s = __builtin_amdgcn_readfirstlane(colidx[e]);
            float w = dinv[s];
            __hip_bfloat162 v = in[(size_t)s * 64 + lane];
            acc0 += w * __bfloat162float(v.x);
            acc1 += w * __bfloat162float(v.y);
        }
        float v0 = di * acc0;
        float v1 = di * acc1;
        if (BIAS) { v0 += bias[2 * lane]; v1 += bias[2 * lane + 1]; }
        if (RELU) { v0 = fmaxf(v0, 0.f); v1 = fmaxf(v1, 0.f); }
        if constexpr (OUT_BF16) {
            __hip_bfloat162* ob = (__hip_bfloat162*)out_;
            __hip_bfloat162 p; p.x = __float2bfloat16(v0); p.y = __float2bfloat16(v1);
            ob[(size_t)i * 64 + lane] = p;
        } else {
            float2* of = (float2*)out_;
            of[(size_t)i * 64 + lane] = make_float2(v0, v1);
        }
    } else {
        // ---- D=64 dual-edge path ----
        const int half = lane >> 5;     // 0: even edges, 1: odd edges
        const int hl   = lane & 31;     // covers cols {2hl, 2hl+1}
        const __hip_bfloat162* in2 = (const __hip_bfloat162*)in_;
        float ax = 0.f, ay = 0.f;
        if (half == 0) {                // self-loop counted once
            __hip_bfloat162 sv = in2[(size_t)i * 32 + hl];
            ax = di * __bfloat162float(sv.x);
            ay = di * __bfloat162float(sv.y);
        }
        int e = rowptr[i];
        const int e1 = rowptr[i + 1];
        for (; e + 16 <= e1; e += 16) {   // 16 edges in flight per wave
            int s[8]; float w[8]; __hip_bfloat162 v[8];
            #pragma unroll
            for (int j = 0; j < 8; ++j) s[j] = colidx[e + 2 * j + half];
            #pragma unroll
            for (int j = 0; j < 8; ++j) w[j] = dinv[s[j]];
            #pragma unroll
            for (int j = 0; j < 8; ++j) v[j] = in2[(size_t)s[j] * 32 + hl];
            #pragma unroll
            for (int j = 0; j < 8; ++j) {
                ax += w[j] * __bfloat162float(v[j].x);
                ay += w[j] * __bfloat162float(v[j].y);
            }
        }
        for (; e + 2 <= e1; e += 2) {     // pair tail, both halves busy
            int s = colidx[e + half];
            float w = dinv[s];
            __hip_bfloat162 v = in2[(size_t)s * 32 + hl];
            ax += w * __bfloat162float(v.x);
            ay += w * __bfloat162float(v.y);
        }
        if (e < e1) {                     // last odd edge: half 0 only
            int s = __builtin_amdgcn_readfirstlane(colidx[e]);
            float w = dinv[s];
            if (half == 0) {
                __hip_bfloat162 v = in2[(size_t)s * 32 + hl];
                ax += w * __bfloat162float(v.x);
                ay += w * __bfloat162float(v.y);
            }
        }
        ax += __shfl_xor(ax, 32);         // combine even/odd halves
        ay += __shfl_xor(ay, 32);
        if (half == 0) {
            float v0 = di * ax, v1 = di * ay;
            if (BIAS) { v0 += bias[2 * hl]; v1 += bias[2 * hl + 1]; }
            if (RELU) { v0 = fmaxf(v0, 0.f); v1 = fmaxf(v1, 0.f); }
            if constexpr (OUT_BF16) {
                __hip_bfloat162* ob = (__hip_bfloat162*)out_;
                __hip_bfloat162 p; p.x = __float2bfloat16(v0); p.y = __float2bfloat16(v1);
                ob[(size_t)i * 32 + hl] = p;
            } else {
                float2* of = (float2*)out_;
                of[(size_t)i * 32 + hl] = make_float2(v0, v1);
            }
        }
    }
}

// ---------------- driver ----------------

extern "C" void kernel_launch(void* const* d_in, const int* in_sizes, int n_in,
                              void* d_out, int out_size, void* d_ws, size_t ws_size,
                              hipStream_t stream) {
    const float* x  = (const float*)d_in[0];
    const int*   ei = (const int*)d_in[1];
    const float* W1 = (const float*)d_in[2];
    const float* b1 = (const float*)d_in[3];
    const float* W2 = (const float*)d_in[4];
    const float* b2 = (const float*)d_in[5];
    const float* W3 = (const float*)d_in[6];
    const float* b3 = (const float*)d_in[7];

    const int IN = 128;
    const int n  = in_sizes[0] / IN;   // 50000
    const int E  = in_sizes[1] / 2;    // 800000

    char* ws = (char*)d_ws;
    size_t off = 0;
    auto alloc = [&](size_t bytes) {
        char* p = ws + off;
        off += (bytes + 255) & ~(size_t)255;
        return p;
    };
    __hip_bfloat16* hA_bf = (__hip_bfloat16*)alloc((size_t)n * 128 * 2);  // 12.8 MB (h1 pre-agg)
    float*          bufB  = (float*)alloc((size_t)n * 128 * 4);           // 25.6 MB (h1 post-agg)
    __hip_bfloat16* hC_bf = (__hip_bfloat16*)alloc((size_t)n * 64 * 2);   //  6.4 MB (h1@W2)
    __hip_bfloat16* hD_bf = (__hip_bfloat16*)alloc((size_t)n * 64 * 2);   //  6.4 MB (h2)
    float*          bufE  = (float*)alloc((size_t)n * 64 * 4);            // 12.8 MB (Agg(h2))
    int*   rowptr = (int*)  alloc(((size_t)n + 1) * sizeof(int));
    float* dinv   = (float*)alloc((size_t)n * sizeof(float));
    int*   colidx = (int*)  alloc((size_t)E * sizeof(int));               //  3.2 MB
    unsigned int* tmp = (unsigned int*)alloc((size_t)E * sizeof(unsigned int)); // 3.2 MB
    int*   hist_b = (int*)  alloc((size_t)256 * SORT_BLOCKS * sizeof(int)); // 256 KB
    int*   btot   = (int*)  alloc(256 * sizeof(int));
    int*   bstart = (int*)  alloc(257 * sizeof(int));

    const int nbucket = ceil_div(n, 256);          // 196 (<= 256)
    const int chunk   = ceil_div(E, SORT_BLOCKS);  // 3125

    // ---- D1: CSR coarse histogram ∥ gemm1 (independent work, one dispatch) ----
    const int gemm1_blocks = ceil_div(n, 64) * 2;  // N=128 -> 2 col tiles
    hist_gemm_kernel<128, 128, true><<<SORT_BLOCKS + gemm1_blocks, 256, 0, stream>>>(
        ei, hist_b, E, nbucket, chunk, x, W1, hA_bf, n);

    // ---- CSR build rest ----
    row_scan_kernel<<<nbucket, 256, 0, stream>>>(hist_b, btot);
    bucket_scatter_kernel<<<SORT_BLOCKS, 256, 0, stream>>>(ei, hist_b, btot, bstart, tmp, E, nbucket, chunk);
    csr_build_kernel<<<nbucket, 256, 0, stream>>>(tmp, bstart, rowptr, dinv, colidx, n, E);

    // ---- Layer 1 agg (D=128, bf16 gather) ----
    agg_kernel<128, true, true, false><<<ceil_div(n, 4), 256, 0, stream>>>(
        hA_bf, b1, rowptr, colidx, dinv, bufB, n);

    // ---- Layer 2: gemm2 then agg2 (D=64 dual-edge) ----
    dim3 g2(ceil_div(n, 64), 1);
    gemm_mfma_kernel<128, 64, false, true><<<g2, 256, 0, stream>>>(bufB, W2, nullptr, hC_bf, n);
    agg_kernel<64, true, true, true><<<ceil_div(n, 4), 256, 0, stream>>>(
        hC_bf, b2, rowptr, colidx, dinv, hD_bf, n);

    // ---- Layer 3: agg3 (D=64 dual-edge) then gemm3 ----
    agg_kernel<64, false, false, false><<<ceil_div(n, 4), 256, 0, stream>>>(
        hD_bf, nullptr, rowptr, colidx, dinv, bufE, n);
    dim3 g3(ceil_div(n, 64), 2);
    gemm_mfma_kernel<64, 128, true, false><<<g3, 256, 0, stream>>>(bufE, W3, b3, d_out, n);
}